// Round 9
// baseline (191.052 us; speedup 1.0000x reference)
//
#include <hip/hip_runtime.h>
#include <cstdint>
#include <cstddef>

#define HH 2048
#define WW 2048
#define NPIX (HH * WW)
#define EPS_NMS 1e-5f
#define EPS_DIV 1e-8f
#define NEG_INF (-3.402823466e+38f)
#define ROWS 8            // proven geometry: 256thr x 4 cols x 8 rows
#define LCAP 2048         // worst-case candidates per 1024x8 region (1 per 2x2)
#define SBUF_CAP 256      // per-block survivor buffer (expected ~12)
#define SG_CAP 7680       // max selected keys; 60KB LDS stage in rank phase
#define NBIN 2048         // 11-bit radix bins (fallback)
#define RANK_BLOCKS 128   // fast path: 128 blocks x 64 keys = 8192 slots >= SG_CAP;
                          // 4x less SG staging traffic than 512 blocks (L3 is
                          // writeback-contended by the harness workspace fill)
#define CREW 64           // fallback radix crew (co-resident: first 64)
#define RB_ELEMS 64       // keys ranked per block (4 waves x 16)
#define BUFCAP 1024       // fallback per-crew-block compact buffer (u64)
// Fast-path threshold: candidate values are maxima of 27 U(0,1);
// count(val >= T) = NPIX*(1-T^27)/27. T=0.99854 -> ~6000 in [K, SG_CAP].
// Exactness-safe: survivor-buffer overflow or m outside [K,SG_CAP] -> radix fallback.
#define T0F 0.99854f

typedef unsigned long long u64;

// ---- workspace layout (bytes) ----
// [0,128)       : uint32 cnt[32]: 0=n_cand 1=n_sel_fb 4=ovf_flag 5=n_sel_fast
// [128,3584)    : 6 tree barriers, 576B each (root line + 8 group lines) [fallback only]
// [4096,12288)  : uint32 hist0[2048]  (fallback only; memset-zeroed)
// [12288,20480) : uint32 hist1[2048]
// [20480,81920) : SG u64[7680]   (fast path: appended by nms)
// [98304,...)   : candidates u64[cap]  (fallback input)

__device__ __forceinline__ float max3(float a, float b, float c) {
    return fmaxf(a, fmaxf(b, c));
}

__device__ __forceinline__ unsigned int aload(const unsigned int* p) {
    return __hip_atomic_load(p, __ATOMIC_RELAXED, __HIP_MEMORY_SCOPE_AGENT);
}

// tree barrier for exactly CREW(=64) co-resident crew blocks; 8 groups x 8.
// (fallback path only — never taken on expected data)
__device__ __forceinline__ void gbar(char* base, unsigned int crewid) {
    __syncthreads();
    if (threadIdx.x == 0) {
        unsigned int* root = (unsigned int*)base;
        unsigned int* gc = (unsigned int*)(base + 64 + ((crewid & 7u) << 6));
        __threadfence();
        if (atomicAdd(gc, 1u) == 7u) atomicAdd(root, 1u);
        while (aload(root) < 8u) __builtin_amdgcn_s_sleep(1);
        __threadfence();
    }
    __syncthreads();
}

// Redundant deterministic radix pick (fallback): every crew block reads the same
// global hist and computes the same boundary bin + remaining-K.
__device__ __forceinline__ void pick_bin(const unsigned int* __restrict__ hg,
                                         unsigned int remk_in,
                                         unsigned int* s,
                                         unsigned int* sh_bin,
                                         unsigned int* sh_rem)
{
    const int tid = threadIdx.x;
    unsigned int bins[8], csum = 0;
    #pragma unroll
    for (int i = 0; i < 8; ++i) { bins[i] = aload(&hg[tid * 8 + i]); csum += bins[i]; }
    s[tid] = csum;
    __syncthreads();
    for (int off = 1; off < 256; off <<= 1) {
        unsigned int v = (tid + off < 256) ? s[tid + off] : 0u;
        __syncthreads(); s[tid] += v; __syncthreads();
    }
    unsigned int incl = s[tid], excl = incl - csum, total = s[0];
    if (tid == 0 && total < remk_in) { *sh_bin = 0u; *sh_rem = remk_in; }   // degenerate
    if (incl >= remk_in && excl < remk_in) {
        unsigned int cum = excl; int b = 7;
        for (; b > 0; --b) { cum += bins[b]; if (cum >= remk_in) break; }
        if (cum < remk_in) cum += bins[0];
        *sh_bin = (unsigned int)(tid * 8 + b);
        *sh_rem = remk_in - (cum - bins[b]);
    }
    __syncthreads();
}

// centroid fit + LAF compose for one selected key
__device__ __forceinline__ void finalize_key(
    u64 my_key, unsigned int rank,
    const float* __restrict__ low, const float* __restrict__ cur,
    const float* __restrict__ high, const float* __restrict__ aff,
    float* __restrict__ out, int K)
{
    float val = __uint_as_float((unsigned int)(my_key >> 32));
    unsigned int idx = ~((unsigned int)my_key);
    out[rank] = val;
    float* laf = out + K + (size_t)rank * 6;
    int y = (int)(idx >> 11), x = (int)(idx & (WW - 1));
    const float ccw[3] = {-0.5f, 0.5f, 1.5f};
    float den = 0.0f, nz = 0.0f, ny = 0.0f, nx = 0.0f;
    #pragma unroll
    for (int dy = -1; dy <= 1; ++dy) {
        int yy = y + dy;
        if (yy < 0 || yy >= HH) continue;
        #pragma unroll
        for (int dx = -1; dx <= 1; ++dx) {
            int xx = x + dx;
            if (xx < 0 || xx >= WW) continue;
            int jj = yy * WW + xx;
            float v0 = low[jj], v1 = cur[jj], v2 = high[jj];
            float ssum = v0 + v1 + v2;
            den += ssum;
            nz += -0.5f * v0 + 0.5f * v1 + 1.5f * v2;
            ny += ccw[dy + 1] * ssum;
            nx += ccw[dx + 1] * ssum;
        }
    }
    float inv = 1.0f / (den + EPS_DIV);
    float s_n = (nz * inv) * (1.0f / 2048.0f);
    float y_n = (ny * inv + (float)y) * (1.0f / 2048.0f);
    float x_n = (nx * inv + (float)x) * (1.0f / 2048.0f);
    float a0 = aff[idx], a1 = aff[NPIX + idx];
    float a2 = aff[2 * NPIX + idx], a3 = aff[3 * NPIX + idx];
    laf[0] = s_n * a0; laf[1] = s_n * a1; laf[2] = x_n;
    laf[3] = s_n * a2; laf[4] = s_n * a3; laf[5] = y_n;
}

// Deep-pipelined rolling-row NMS (proven R8): 256 threads x 4 cols (float4) x
// 8 rows, 6-deep cube-row ring + 4-deep oct ring. Effective BW is capped
// (~1.6 TB/s) by L3 writeback contention from the harness workspace fill, so
// this kernel sits at its byte floor (~60 MB). Epilogue appends survivors
// (key >= T0) directly to SG; kernel boundary is the only sync.
__global__ __launch_bounds__(256) void nms_map_kernel(
    const float* __restrict__ low, const float* __restrict__ cur,
    const float* __restrict__ high, const float* __restrict__ oct,
    float* __restrict__ oct_out, float* __restrict__ vals_out, int n7k,
    u64* __restrict__ cand, unsigned int* __restrict__ cnt,
    u64* __restrict__ SG, unsigned int cap)
{
    __shared__ unsigned int lcount, lbase, lT, lsb;
    __shared__ u64 lcand[LCAP];
    __shared__ u64 sbuf[SBUF_CAP];

    const int tid = threadIdx.x;
    const int lane = tid & 63;
    const int x4 = blockIdx.x * 1024 + tid * 4;
    const int y0 = blockIdx.y * ROWS;
    if (tid == 0) { lcount = 0u; lT = 0u; }

    if (blockIdx.y == 0) {                    // zero vals+lafs region (fallback safety)
        int n4 = n7k >> 2;
        float4* vz = (float4*)vals_out;
        for (int i = blockIdx.x * 256 + tid; i < n4; i += gridDim.x * 256)
            vz[i] = make_float4(0.f, 0.f, 0.f, 0.f);
    }
    __syncthreads();

    // 6-deep ring over cube rows r = row-(y0-1) in [0,10); 4-deep oct ring
    float4 Lb[6], Cb[6], Hb[6], Ob[4];
    float eLl[6], eLc[6], eLh[6], eRl[6], eRc[6], eRh[6];

    // issue cube row r (global row y0-1+r) into ring slot r%6
    #define ISSUE(r) {                                                            \
        const int sl = (r) % 6;                                                   \
        int tt = y0 - 1 + (r);                                                    \
        if (tt >= 0 && tt < HH) {                                                 \
            int jj = tt * WW + x4;                                                \
            Lb[sl] = *(const float4*)(low  + jj);                                 \
            Cb[sl] = *(const float4*)(cur  + jj);                                 \
            Hb[sl] = *(const float4*)(high + jj);                                 \
            bool doL = (lane == 0)  && (x4 > 0);                                  \
            bool doR = (lane == 63) && (x4 + 4 < WW);                             \
            eLl[sl] = doL ? low[jj - 1]  : NEG_INF;                               \
            eLc[sl] = doL ? cur[jj - 1]  : NEG_INF;                               \
            eLh[sl] = doL ? high[jj - 1] : NEG_INF;                               \
            eRl[sl] = doR ? low[jj + 4]  : NEG_INF;                               \
            eRc[sl] = doR ? cur[jj + 4]  : NEG_INF;                               \
            eRh[sl] = doR ? high[jj + 4] : NEG_INF;                               \
        } else {                                                                  \
            Lb[sl] = Cb[sl] = Hb[sl] =                                            \
                make_float4(NEG_INF, NEG_INF, NEG_INF, NEG_INF);                  \
            eLl[sl] = eLc[sl] = eLh[sl] = NEG_INF;                                \
            eRl[sl] = eRc[sl] = eRh[sl] = NEG_INF;                                \
        }                                                                         \
    }

    // z-max + horizontal 3-window max of cube row r (ring slot r%6)
    #define CONSUME(r, hzO) {                                                     \
        const int sl = (r) % 6;                                                   \
        float4 l = Lb[sl], c = Cb[sl], hh = Hb[sl];                               \
        float4 z;                                                                 \
        z.x = max3(l.x, c.x, hh.x);                                               \
        z.y = max3(l.y, c.y, hh.y);                                               \
        z.z = max3(l.z, c.z, hh.z);                                               \
        z.w = max3(l.w, c.w, hh.w);                                               \
        float zeL = max3(eLl[sl], eLc[sl], eLh[sl]);                              \
        float zeR = max3(eRl[sl], eRc[sl], eRh[sl]);                              \
        float zl = __shfl_up(z.w, 1, 64);                                         \
        float zr = __shfl_down(z.x, 1, 64);                                       \
        if (lane == 0)  zl = zeL;                                                 \
        if (lane == 63) zr = zeR;                                                 \
        hzO.x = max3(zl,  z.x, z.y);                                              \
        hzO.y = max3(z.x, z.y, z.z);                                              \
        hzO.z = max3(z.y, z.z, z.w);                                              \
        hzO.w = max3(z.z, z.w, zr);                                               \
    }

    float4 hzA, hzB, hzC;
    // prologue: issue 5 cube rows + 3 oct rows ahead
    ISSUE(0) ISSUE(1) ISSUE(2) ISSUE(3) ISSUE(4)
    Ob[0] = *(const float4*)(oct + (y0 + 0) * WW + x4);
    Ob[1] = *(const float4*)(oct + (y0 + 1) * WW + x4);
    Ob[2] = *(const float4*)(oct + (y0 + 2) * WW + x4);
    CONSUME(0, hzA)
    CONSUME(1, hzB)

    #pragma unroll
    for (int j = 0; j < ROWS; ++j) {
        int y = y0 + j;
        if (j + 5 <= 9) ISSUE(j + 5)                          // ring rows 5..9
        if (j + 3 < ROWS)                                     // oct rows y0+3 .. y0+7
            Ob[(j + 3) & 3] = *(const float4*)(oct + (y + 3) * WW + x4);
        CONSUME(j + 2, hzC)

        int idx = y * WW + x4;
        float4 o = Ob[j & 3];
        float4 cv = Cb[(j + 1) % 6];     // cur at row y (ring row r=j+1); slot
                                         // not overwritten until ISSUE(j+7) at j+2
        bool yin = (y > 0) && (y < HH - 1);
        float4 ov;
        #define DO_COMP(comp, i)  {                                               \
            float m = max3(hzA.comp, hzB.comp, hzC.comp);                         \
            int xg = x4 + (i);                                                    \
            bool interior = yin && (xg > 0) && (xg < WW - 1);                     \
            float nm = (((cv.comp - m + EPS_NMS) > 0.0f) && interior)             \
                       ? cv.comp * (1.0f - o.comp) : 0.0f;                        \
            ov.comp = (float)((unsigned char)(o.comp + nm));                      \
            if (nm > 0.0f) {                                                      \
                unsigned int p = atomicAdd(&lcount, 1u);                          \
                if (p < LCAP)                                                     \
                    lcand[p] = (((u64)__float_as_uint(nm)) << 32)                 \
                               | (unsigned int)(~(idx + (i)));                    \
            }                                                                     \
        }
        DO_COMP(x, 0) DO_COMP(y, 1) DO_COMP(z, 2) DO_COMP(w, 3)
        #undef DO_COMP
        *(float4*)(oct_out + idx) = ov;
        hzA = hzB; hzB = hzC;
    }
    #undef ISSUE
    #undef CONSUME

    // flush candidates + collect survivors (key >= T0) into LDS
    __syncthreads();
    unsigned int c = lcount < LCAP ? lcount : LCAP;
    if (tid == 0) lbase = atomicAdd(&cnt[0], c);
    __syncthreads();
    unsigned int base = lbase;
    const u64 T0KEY = ((u64)__float_as_uint(T0F)) << 32;
    for (unsigned int i = tid; i < c; i += 256) {
        u64 k = lcand[i];
        unsigned int p = base + i;
        if (p < cap) cand[p] = k;
        if (k >= T0KEY) {                       // survivor append NOT gated by cap
            unsigned int q = atomicAdd(&lT, 1u);
            if (q < SBUF_CAP) sbuf[q] = k;
        }
    }
    __syncthreads();
    unsigned int t = lT;
    if (tid == 0) {
        if (t > (unsigned int)SBUF_CAP) atomicExch(&cnt[4], 1u);   // -> fallback
        lsb = t ? atomicAdd(&cnt[5], t) : 0u;   // true count even if writes capped
    }
    __syncthreads();
    unsigned int nb = t < (unsigned int)SBUF_CAP ? t : (unsigned int)SBUF_CAP;
    unsigned int sb = lsb;
    for (unsigned int i = tid; i < nb; i += 256) {
        unsigned int p = sb + i;
        if (p < (unsigned int)SG_CAP) SG[p] = sbuf[i];
    }
}

// Rank + finalize. FAST PATH (expected): m = cnt[5] in [K, SG_CAP], no overflow
// -> 128 blocks, ZERO grid barriers: every block stages SG (m keys) into LDS;
// wave w ranks 16 keys (16 compares amortize each ds_read_b64); 64 threads
// finalize. 128 x 64 = 8192 slots >= SG_CAP. 4x less staging traffic than 512
// blocks — staging is the dominant term under the L3 writeback contention.
// FALLBACK (exact-safe): first 64 blocks run the 2-pass radix over cand[]
// with tree barriers, then chunked rank (proven R2-R5 structure).
__global__ __launch_bounds__(256) void rank_kernel(
    const u64* __restrict__ cand, u64* __restrict__ SG,
    unsigned int* __restrict__ cnt,
    unsigned int* __restrict__ hist0, unsigned int* __restrict__ hist1,
    unsigned int cap, int K,
    const float* __restrict__ low, const float* __restrict__ cur,
    const float* __restrict__ high, const float* __restrict__ aff,
    float* __restrict__ out)
{
    __shared__ u64 sgl[SG_CAP];
    __shared__ unsigned int s[256];
    __shared__ unsigned int rnk[RB_ELEMS];
    __shared__ unsigned int sh_bin, sh_rem, lc, lb;
    unsigned int* h = (unsigned int*)sgl;   // fallback hist, bytes [0, 8192)
    u64* buf = sgl + 2048;                  // fallback compact buf

    const int tid = threadIdx.x;
    const int bid = blockIdx.x;
    const unsigned int wave = (unsigned int)tid >> 6, ln = (unsigned int)tid & 63u;

    unsigned int m = cnt[5];
    bool fast = (cnt[4] == 0u) && (m >= (unsigned int)K) && (m <= (unsigned int)SG_CAP);

    if (fast) {
        unsigned int kbase = (unsigned int)bid * RB_ELEMS;
        if (kbase >= m) return;                 // block has no keys
        for (unsigned int i = tid; i < m; i += 256) sgl[i] = SG[i];
        __syncthreads();

        // wave w ranks keys e = kbase + w*16 + i, i in [0,16)
        u64 my[16];
        unsigned int r[16];
        #pragma unroll
        for (int i = 0; i < 16; ++i) {
            unsigned int e = kbase + wave * 16u + (unsigned int)i;
            my[i] = (e < m) ? sgl[e] : ~0ull;
            r[i] = 0u;
        }
        for (unsigned int j2 = ln; j2 < m; j2 += 64) {
            u64 key = sgl[j2];
            #pragma unroll
            for (int i = 0; i < 16; ++i) r[i] += (unsigned int)(key > my[i]);
        }
        #pragma unroll
        for (int i = 0; i < 16; ++i) {
            #pragma unroll
            for (int off = 32; off > 0; off >>= 1)
                r[i] += __shfl_down(r[i], off, 64);
            if (ln == 0) rnk[wave * 16 + i] = r[i];
        }
        __syncthreads();

        if (tid < RB_ELEMS) {
            unsigned int e = kbase + (unsigned int)tid;
            if (e < m) {
                unsigned int rank = rnk[tid];
                if (rank < (unsigned int)K)
                    finalize_key(sgl[e], rank, low, cur, high, aff, out, K);
            }
        }
        return;
    }

    // ---------------- fallback: exact 2-pass radix (crew = first 64 blocks) ----
    if (bid >= CREW) return;
    const unsigned int crewid = (unsigned int)bid;
    char* barb = (char*)cnt + 128;          // 6 tree barriers, 576B each
    unsigned int n0 = cnt[0];
    unsigned int n = n0; if (n > cap) n = cap;
    const unsigned int stride = CREW * 256;

    for (int i = tid; i < NBIN; i += 256) h[i] = 0u;
    __syncthreads();
    for (unsigned int i = crewid * 256 + tid; i < n; i += stride)
        atomicAdd(&h[(unsigned int)(cand[i] >> 53)], 1u);
    __syncthreads();
    for (int i = tid; i < NBIN; i += 256) { unsigned int v = h[i]; if (v) atomicAdd(&hist0[i], v); }
    gbar(barb, crewid);                                    // barrier 0
    pick_bin(hist0, (unsigned int)K, s, &sh_bin, &sh_rem);
    const unsigned int prefix = sh_bin;
    const unsigned int remk   = sh_rem;

    for (int i = tid; i < NBIN; i += 256) h[i] = 0u;
    __syncthreads();
    for (unsigned int i = crewid * 256 + tid; i < n; i += stride) {
        unsigned int k32 = (unsigned int)(cand[i] >> 32);
        if ((k32 >> 21) == prefix) atomicAdd(&h[(k32 >> 10) & (NBIN - 1u)], 1u);
    }
    __syncthreads();
    for (int i = tid; i < NBIN; i += 256) { unsigned int v = h[i]; if (v) atomicAdd(&hist1[i], v); }
    gbar(barb + 576, crewid);                              // barrier 1
    pick_bin(hist1, remk, s, &sh_bin, &sh_rem);
    const unsigned int T = (prefix << 11) | sh_bin;

    if (tid == 0) lc = 0u;
    __syncthreads();
    for (unsigned int i = crewid * 256 + tid; i < n; i += stride) {
        u64 key = cand[i];
        if ((unsigned int)(key >> 42) >= T) {
            unsigned int p = atomicAdd(&lc, 1u);
            if (p < BUFCAP) buf[p] = key;
        }
    }
    __syncthreads();
    unsigned int cc = lc < BUFCAP ? lc : BUFCAP;
    if (tid == 0) lb = atomicAdd(&cnt[1], cc);
    __syncthreads();
    unsigned int b2 = lb;
    for (unsigned int i = tid; i < cc; i += 256) {
        unsigned int p = b2 + i;
        if (p < (unsigned int)SG_CAP) SG[p] = buf[i];
    }
    gbar(barb + 2 * 576, crewid);                          // barrier 2
    unsigned int m2 = aload(&cnt[1]); if (m2 > (unsigned int)SG_CAP) m2 = SG_CAP;

    for (unsigned int i = tid; i < m2; i += 256) sgl[i] = SG[i];
    __syncthreads();
    for (unsigned int chunk = crewid * RB_ELEMS; chunk < m2;
         chunk += (unsigned int)CREW * RB_ELEMS) {
        u64 my[16];
        unsigned int r[16];
        #pragma unroll
        for (int i = 0; i < 16; ++i) {
            unsigned int e = chunk + wave * 16 + i;
            my[i] = (e < m2) ? sgl[e] : ~0ull;
            r[i] = 0u;
        }
        for (unsigned int j = ln; j < m2; j += 64) {
            u64 key = sgl[j];
            #pragma unroll
            for (int i = 0; i < 16; ++i) r[i] += (unsigned int)(key > my[i]);
        }
        #pragma unroll
        for (int i = 0; i < 16; ++i) {
            #pragma unroll
            for (int off = 32; off > 0; off >>= 1)
                r[i] += __shfl_down(r[i], off, 64);
            if (ln == 0) rnk[wave * 16 + i] = r[i];
        }
        __syncthreads();
        if (tid < RB_ELEMS) {
            unsigned int e = chunk + (unsigned int)tid;
            if (e < m2) {
                unsigned int rank = rnk[tid];
                if (rank < (unsigned int)K)
                    finalize_key(sgl[e], rank, low, cur, high, aff, out, K);
            }
        }
        __syncthreads();
    }
}

extern "C" void kernel_launch(void* const* d_in, const int* in_sizes, int n_in,
                              void* d_out, int out_size, void* d_ws, size_t ws_size,
                              hipStream_t stream) {
    const float* low  = (const float*)d_in[0];
    const float* cur  = (const float*)d_in[1];
    const float* high = (const float*)d_in[2];
    const float* aff  = (const float*)d_in[3];
    const float* oct  = (const float*)d_in[4];
    int K = (out_size - NPIX) / 7;   // 4096
    float* out = (float*)d_out;

    char* ws = (char*)d_ws;
    unsigned int* cnt   = (unsigned int*)ws;
    unsigned int* hist0 = (unsigned int*)(ws + 4096);
    unsigned int* hist1 = (unsigned int*)(ws + 12288);
    u64* SG             = (u64*)(ws + 20480);
    const size_t cand_off = 98304;
    u64* cand           = (u64*)(ws + cand_off);
    size_t cap_sz = ws_size > cand_off ? (ws_size - cand_off) / 8 : 0;
    if (cap_sz > (size_t)NPIX) cap_sz = (size_t)NPIX;
    unsigned int cap = (unsigned int)cap_sz;

    hipMemsetAsync(ws, 0, 20480, stream);   // cnt + barriers + hist0 + hist1

    dim3 gb(WW / 1024, HH / ROWS, 1);       // (2, 256) = 512 blocks
    nms_map_kernel<<<gb, 256, 0, stream>>>(low, cur, high, oct,
                                           out + (size_t)7 * K, out, 7 * K,
                                           cand, cnt, SG, cap);
    rank_kernel<<<RANK_BLOCKS, 256, 0, stream>>>(cand, SG, cnt, hist0, hist1,
                                                 cap, K, low, cur, high, aff, out);
}

// Round 10
// 178.284 us; speedup vs baseline: 1.0716x; 1.0716x over previous
//
#include <hip/hip_runtime.h>
#include <cstdint>
#include <cstddef>

#define HH 2048
#define WW 2048
#define NPIX (HH * WW)
#define EPS_NMS 1e-5f
#define EPS_DIV 1e-8f
#define NEG_INF (-3.402823466e+38f)
#define ROWS 8            // proven geometry: 256thr x 4 cols x 8 rows
#define LCAP 2048         // worst-case candidates per 1024x8 region (1 per 2x2)
#define SBUF_CAP 256      // per-block survivor buffer (expected ~12)
#define SG_CAP 7680       // max selected keys; 60KB LDS stage in rank phase
#define NBIN 2048         // 11-bit radix bins (fallback)
#define RANK_BLOCKS 512   // fast path: 512 blocks (2/CU) — rank staging is
                          // LLC-latency-bound; needs co-resident waves (R9 lesson:
                          // 128 blocks = -12us). Wave g ranks 4 keys, zero barriers.
#define CREW 64           // fallback radix crew (co-resident: first 64)
#define RB_ELEMS 64       // fallback: keys ranked per crew block per chunk
#define BUFCAP 1024       // fallback per-crew-block compact buffer (u64)
// Fast-path threshold: candidate values are maxima of 27 U(0,1);
// count(val >= T) = NPIX*(1-T^27)/27. T=0.99854 -> ~6000 in [K, SG_CAP].
// Exactness-safe: survivor-buffer overflow or m outside [K,SG_CAP] -> radix fallback.
#define T0F 0.99854f

typedef unsigned long long u64;

// ---- workspace layout (bytes) ----
// [0,128)       : uint32 cnt[32]: 0=n_cand 1=n_sel_fb 4=ovf_flag 5=n_sel_fast
// [128,3584)    : 6 tree barriers, 576B each (root line + 8 group lines) [fallback only]
// [4096,12288)  : uint32 hist0[2048]  (fallback only; memset-zeroed)
// [12288,20480) : uint32 hist1[2048]
// [20480,81920) : SG u64[7680]   (fast path: appended by nms)
// [98304,...)   : candidates u64[cap]  (fallback input)

__device__ __forceinline__ float max3(float a, float b, float c) {
    return fmaxf(a, fmaxf(b, c));
}

__device__ __forceinline__ unsigned int aload(const unsigned int* p) {
    return __hip_atomic_load(p, __ATOMIC_RELAXED, __HIP_MEMORY_SCOPE_AGENT);
}

// tree barrier for exactly CREW(=64) co-resident crew blocks; 8 groups x 8.
// (fallback path only — never taken on expected data)
__device__ __forceinline__ void gbar(char* base, unsigned int crewid) {
    __syncthreads();
    if (threadIdx.x == 0) {
        unsigned int* root = (unsigned int*)base;
        unsigned int* gc = (unsigned int*)(base + 64 + ((crewid & 7u) << 6));
        __threadfence();
        if (atomicAdd(gc, 1u) == 7u) atomicAdd(root, 1u);
        while (aload(root) < 8u) __builtin_amdgcn_s_sleep(1);
        __threadfence();
    }
    __syncthreads();
}

// Redundant deterministic radix pick (fallback): every crew block reads the same
// global hist and computes the same boundary bin + remaining-K.
__device__ __forceinline__ void pick_bin(const unsigned int* __restrict__ hg,
                                         unsigned int remk_in,
                                         unsigned int* s,
                                         unsigned int* sh_bin,
                                         unsigned int* sh_rem)
{
    const int tid = threadIdx.x;
    unsigned int bins[8], csum = 0;
    #pragma unroll
    for (int i = 0; i < 8; ++i) { bins[i] = aload(&hg[tid * 8 + i]); csum += bins[i]; }
    s[tid] = csum;
    __syncthreads();
    for (int off = 1; off < 256; off <<= 1) {
        unsigned int v = (tid + off < 256) ? s[tid + off] : 0u;
        __syncthreads(); s[tid] += v; __syncthreads();
    }
    unsigned int incl = s[tid], excl = incl - csum, total = s[0];
    if (tid == 0 && total < remk_in) { *sh_bin = 0u; *sh_rem = remk_in; }   // degenerate
    if (incl >= remk_in && excl < remk_in) {
        unsigned int cum = excl; int b = 7;
        for (; b > 0; --b) { cum += bins[b]; if (cum >= remk_in) break; }
        if (cum < remk_in) cum += bins[0];
        *sh_bin = (unsigned int)(tid * 8 + b);
        *sh_rem = remk_in - (cum - bins[b]);
    }
    __syncthreads();
}

// centroid fit + LAF compose for one selected key
__device__ __forceinline__ void finalize_key(
    u64 my_key, unsigned int rank,
    const float* __restrict__ low, const float* __restrict__ cur,
    const float* __restrict__ high, const float* __restrict__ aff,
    float* __restrict__ out, int K)
{
    float val = __uint_as_float((unsigned int)(my_key >> 32));
    unsigned int idx = ~((unsigned int)my_key);
    out[rank] = val;
    float* laf = out + K + (size_t)rank * 6;
    int y = (int)(idx >> 11), x = (int)(idx & (WW - 1));
    const float ccw[3] = {-0.5f, 0.5f, 1.5f};
    float den = 0.0f, nz = 0.0f, ny = 0.0f, nx = 0.0f;
    #pragma unroll
    for (int dy = -1; dy <= 1; ++dy) {
        int yy = y + dy;
        if (yy < 0 || yy >= HH) continue;
        #pragma unroll
        for (int dx = -1; dx <= 1; ++dx) {
            int xx = x + dx;
            if (xx < 0 || xx >= WW) continue;
            int jj = yy * WW + xx;
            float v0 = low[jj], v1 = cur[jj], v2 = high[jj];
            float ssum = v0 + v1 + v2;
            den += ssum;
            nz += -0.5f * v0 + 0.5f * v1 + 1.5f * v2;
            ny += ccw[dy + 1] * ssum;
            nx += ccw[dx + 1] * ssum;
        }
    }
    float inv = 1.0f / (den + EPS_DIV);
    float s_n = (nz * inv) * (1.0f / 2048.0f);
    float y_n = (ny * inv + (float)y) * (1.0f / 2048.0f);
    float x_n = (nx * inv + (float)x) * (1.0f / 2048.0f);
    float a0 = aff[idx], a1 = aff[NPIX + idx];
    float a2 = aff[2 * NPIX + idx], a3 = aff[3 * NPIX + idx];
    laf[0] = s_n * a0; laf[1] = s_n * a1; laf[2] = x_n;
    laf[3] = s_n * a2; laf[4] = s_n * a3; laf[5] = y_n;
}

// Deep-pipelined rolling-row NMS (proven R8): 256 threads x 4 cols (float4) x
// 8 rows, 6-deep cube-row ring + 4-deep oct ring. Effective BW is capped
// (~1.6 TB/s) by L3 writeback contention from the harness workspace fill, so
// this kernel sits at its byte floor (~60 MB). Epilogue appends survivors
// (key >= T0) directly to SG; kernel boundary is the only sync.
__global__ __launch_bounds__(256) void nms_map_kernel(
    const float* __restrict__ low, const float* __restrict__ cur,
    const float* __restrict__ high, const float* __restrict__ oct,
    float* __restrict__ oct_out, float* __restrict__ vals_out, int n7k,
    u64* __restrict__ cand, unsigned int* __restrict__ cnt,
    u64* __restrict__ SG, unsigned int cap)
{
    __shared__ unsigned int lcount, lbase, lT, lsb;
    __shared__ u64 lcand[LCAP];
    __shared__ u64 sbuf[SBUF_CAP];

    const int tid = threadIdx.x;
    const int lane = tid & 63;
    const int x4 = blockIdx.x * 1024 + tid * 4;
    const int y0 = blockIdx.y * ROWS;
    if (tid == 0) { lcount = 0u; lT = 0u; }

    if (blockIdx.y == 0) {                    // zero vals+lafs region (fallback safety)
        int n4 = n7k >> 2;
        float4* vz = (float4*)vals_out;
        for (int i = blockIdx.x * 256 + tid; i < n4; i += gridDim.x * 256)
            vz[i] = make_float4(0.f, 0.f, 0.f, 0.f);
    }
    __syncthreads();

    // 6-deep ring over cube rows r = row-(y0-1) in [0,10); 4-deep oct ring
    float4 Lb[6], Cb[6], Hb[6], Ob[4];
    float eLl[6], eLc[6], eLh[6], eRl[6], eRc[6], eRh[6];

    // issue cube row r (global row y0-1+r) into ring slot r%6
    #define ISSUE(r) {                                                            \
        const int sl = (r) % 6;                                                   \
        int tt = y0 - 1 + (r);                                                    \
        if (tt >= 0 && tt < HH) {                                                 \
            int jj = tt * WW + x4;                                                \
            Lb[sl] = *(const float4*)(low  + jj);                                 \
            Cb[sl] = *(const float4*)(cur  + jj);                                 \
            Hb[sl] = *(const float4*)(high + jj);                                 \
            bool doL = (lane == 0)  && (x4 > 0);                                  \
            bool doR = (lane == 63) && (x4 + 4 < WW);                             \
            eLl[sl] = doL ? low[jj - 1]  : NEG_INF;                               \
            eLc[sl] = doL ? cur[jj - 1]  : NEG_INF;                               \
            eLh[sl] = doL ? high[jj - 1] : NEG_INF;                               \
            eRl[sl] = doR ? low[jj + 4]  : NEG_INF;                               \
            eRc[sl] = doR ? cur[jj + 4]  : NEG_INF;                               \
            eRh[sl] = doR ? high[jj + 4] : NEG_INF;                               \
        } else {                                                                  \
            Lb[sl] = Cb[sl] = Hb[sl] =                                            \
                make_float4(NEG_INF, NEG_INF, NEG_INF, NEG_INF);                  \
            eLl[sl] = eLc[sl] = eLh[sl] = NEG_INF;                                \
            eRl[sl] = eRc[sl] = eRh[sl] = NEG_INF;                                \
        }                                                                         \
    }

    // z-max + horizontal 3-window max of cube row r (ring slot r%6)
    #define CONSUME(r, hzO) {                                                     \
        const int sl = (r) % 6;                                                   \
        float4 l = Lb[sl], c = Cb[sl], hh = Hb[sl];                               \
        float4 z;                                                                 \
        z.x = max3(l.x, c.x, hh.x);                                               \
        z.y = max3(l.y, c.y, hh.y);                                               \
        z.z = max3(l.z, c.z, hh.z);                                               \
        z.w = max3(l.w, c.w, hh.w);                                               \
        float zeL = max3(eLl[sl], eLc[sl], eLh[sl]);                              \
        float zeR = max3(eRl[sl], eRc[sl], eRh[sl]);                              \
        float zl = __shfl_up(z.w, 1, 64);                                         \
        float zr = __shfl_down(z.x, 1, 64);                                       \
        if (lane == 0)  zl = zeL;                                                 \
        if (lane == 63) zr = zeR;                                                 \
        hzO.x = max3(zl,  z.x, z.y);                                              \
        hzO.y = max3(z.x, z.y, z.z);                                              \
        hzO.z = max3(z.y, z.z, z.w);                                              \
        hzO.w = max3(z.z, z.w, zr);                                               \
    }

    float4 hzA, hzB, hzC;
    // prologue: issue 5 cube rows + 3 oct rows ahead
    ISSUE(0) ISSUE(1) ISSUE(2) ISSUE(3) ISSUE(4)
    Ob[0] = *(const float4*)(oct + (y0 + 0) * WW + x4);
    Ob[1] = *(const float4*)(oct + (y0 + 1) * WW + x4);
    Ob[2] = *(const float4*)(oct + (y0 + 2) * WW + x4);
    CONSUME(0, hzA)
    CONSUME(1, hzB)

    #pragma unroll
    for (int j = 0; j < ROWS; ++j) {
        int y = y0 + j;
        if (j + 5 <= 9) ISSUE(j + 5)                          // ring rows 5..9
        if (j + 3 < ROWS)                                     // oct rows y0+3 .. y0+7
            Ob[(j + 3) & 3] = *(const float4*)(oct + (y + 3) * WW + x4);
        CONSUME(j + 2, hzC)

        int idx = y * WW + x4;
        float4 o = Ob[j & 3];
        float4 cv = Cb[(j + 1) % 6];     // cur at row y (ring row r=j+1); slot
                                         // not overwritten until ISSUE(j+7) at j+2
        bool yin = (y > 0) && (y < HH - 1);
        float4 ov;
        #define DO_COMP(comp, i)  {                                               \
            float m = max3(hzA.comp, hzB.comp, hzC.comp);                         \
            int xg = x4 + (i);                                                    \
            bool interior = yin && (xg > 0) && (xg < WW - 1);                     \
            float nm = (((cv.comp - m + EPS_NMS) > 0.0f) && interior)             \
                       ? cv.comp * (1.0f - o.comp) : 0.0f;                        \
            ov.comp = (float)((unsigned char)(o.comp + nm));                      \
            if (nm > 0.0f) {                                                      \
                unsigned int p = atomicAdd(&lcount, 1u);                          \
                if (p < LCAP)                                                     \
                    lcand[p] = (((u64)__float_as_uint(nm)) << 32)                 \
                               | (unsigned int)(~(idx + (i)));                    \
            }                                                                     \
        }
        DO_COMP(x, 0) DO_COMP(y, 1) DO_COMP(z, 2) DO_COMP(w, 3)
        #undef DO_COMP
        *(float4*)(oct_out + idx) = ov;
        hzA = hzB; hzB = hzC;
    }
    #undef ISSUE
    #undef CONSUME

    // flush candidates + collect survivors (key >= T0) into LDS
    __syncthreads();
    unsigned int c = lcount < LCAP ? lcount : LCAP;
    if (tid == 0) lbase = atomicAdd(&cnt[0], c);
    __syncthreads();
    unsigned int base = lbase;
    const u64 T0KEY = ((u64)__float_as_uint(T0F)) << 32;
    for (unsigned int i = tid; i < c; i += 256) {
        u64 k = lcand[i];
        unsigned int p = base + i;
        if (p < cap) cand[p] = k;
        if (k >= T0KEY) {                       // survivor append NOT gated by cap
            unsigned int q = atomicAdd(&lT, 1u);
            if (q < SBUF_CAP) sbuf[q] = k;
        }
    }
    __syncthreads();
    unsigned int t = lT;
    if (tid == 0) {
        if (t > (unsigned int)SBUF_CAP) atomicExch(&cnt[4], 1u);   // -> fallback
        lsb = t ? atomicAdd(&cnt[5], t) : 0u;   // true count even if writes capped
    }
    __syncthreads();
    unsigned int nb = t < (unsigned int)SBUF_CAP ? t : (unsigned int)SBUF_CAP;
    unsigned int sb = lsb;
    for (unsigned int i = tid; i < nb; i += 256) {
        unsigned int p = sb + i;
        if (p < (unsigned int)SG_CAP) SG[p] = sbuf[i];
    }
}

// Rank + finalize. FAST PATH (expected): m = cnt[5] in [K, SG_CAP], no overflow
// -> 512 blocks, ZERO grid barriers: every block stages SG into LDS; wave
// g = bid*4+w ranks keys i == g (mod 2048); finalize inline. Partition is by
// SG index, so no cross-block coordination is needed. (R8-proven; R9 showed
// fewer/fatter blocks regress — staging is LLC-latency-bound, wants TLP.)
// FALLBACK (exact-safe): first 64 blocks run the 2-pass radix over cand[]
// with tree barriers, then chunked rank (proven R2-R5 structure).
__global__ __launch_bounds__(256) void rank_kernel(
    const u64* __restrict__ cand, u64* __restrict__ SG,
    unsigned int* __restrict__ cnt,
    unsigned int* __restrict__ hist0, unsigned int* __restrict__ hist1,
    unsigned int cap, int K,
    const float* __restrict__ low, const float* __restrict__ cur,
    const float* __restrict__ high, const float* __restrict__ aff,
    float* __restrict__ out)
{
    __shared__ u64 sgl[SG_CAP];
    __shared__ unsigned int s[256];
    __shared__ unsigned int rnk[RB_ELEMS];
    __shared__ unsigned int sh_bin, sh_rem, lc, lb;
    unsigned int* h = (unsigned int*)sgl;   // fallback hist, bytes [0, 8192)
    u64* buf = sgl + 2048;                  // fallback compact buf

    const int tid = threadIdx.x;
    const int bid = blockIdx.x;
    const unsigned int wave = (unsigned int)tid >> 6, ln = (unsigned int)tid & 63u;

    unsigned int m = cnt[5];
    bool fast = (cnt[4] == 0u) && (m >= (unsigned int)K) && (m <= (unsigned int)SG_CAP);

    if (fast) {
        for (unsigned int i = tid; i < m; i += 256) sgl[i] = SG[i];
        __syncthreads();

        unsigned int g = (unsigned int)bid * 4u + wave;
        u64 my[4];
        unsigned int r[4];
        #pragma unroll
        for (int j = 0; j < 4; ++j) {
            unsigned int i = g + 2048u * (unsigned int)j;
            my[j] = (i < m) ? sgl[i] : ~0ull;
            r[j] = 0u;
        }
        for (unsigned int j2 = ln; j2 < m; j2 += 64) {
            u64 key = sgl[j2];
            #pragma unroll
            for (int j = 0; j < 4; ++j) r[j] += (unsigned int)(key > my[j]);
        }
        #pragma unroll
        for (int j = 0; j < 4; ++j) {
            #pragma unroll
            for (int off = 32; off > 0; off >>= 1)
                r[j] += __shfl_down(r[j], off, 64);
            if (ln == 0) rnk[wave * 4 + j] = r[j];
        }
        __syncthreads();

        if (tid < 16) {
            unsigned int w2 = (unsigned int)tid >> 2, j = (unsigned int)tid & 3u;
            unsigned int i = (unsigned int)bid * 4u + w2 + 2048u * j;
            if (i < m) {
                unsigned int rank = rnk[w2 * 4 + j];
                if (rank < (unsigned int)K)
                    finalize_key(sgl[i], rank, low, cur, high, aff, out, K);
            }
        }
        return;
    }

    // ---------------- fallback: exact 2-pass radix (crew = first 64 blocks) ----
    if (bid >= CREW) return;
    const unsigned int crewid = (unsigned int)bid;
    char* barb = (char*)cnt + 128;          // 6 tree barriers, 576B each
    unsigned int n0 = cnt[0];
    unsigned int n = n0; if (n > cap) n = cap;
    const unsigned int stride = CREW * 256;

    for (int i = tid; i < NBIN; i += 256) h[i] = 0u;
    __syncthreads();
    for (unsigned int i = crewid * 256 + tid; i < n; i += stride)
        atomicAdd(&h[(unsigned int)(cand[i] >> 53)], 1u);
    __syncthreads();
    for (int i = tid; i < NBIN; i += 256) { unsigned int v = h[i]; if (v) atomicAdd(&hist0[i], v); }
    gbar(barb, crewid);                                    // barrier 0
    pick_bin(hist0, (unsigned int)K, s, &sh_bin, &sh_rem);
    const unsigned int prefix = sh_bin;
    const unsigned int remk   = sh_rem;

    for (int i = tid; i < NBIN; i += 256) h[i] = 0u;
    __syncthreads();
    for (unsigned int i = crewid * 256 + tid; i < n; i += stride) {
        unsigned int k32 = (unsigned int)(cand[i] >> 32);
        if ((k32 >> 21) == prefix) atomicAdd(&h[(k32 >> 10) & (NBIN - 1u)], 1u);
    }
    __syncthreads();
    for (int i = tid; i < NBIN; i += 256) { unsigned int v = h[i]; if (v) atomicAdd(&hist1[i], v); }
    gbar(barb + 576, crewid);                              // barrier 1
    pick_bin(hist1, remk, s, &sh_bin, &sh_rem);
    const unsigned int T = (prefix << 11) | sh_bin;

    if (tid == 0) lc = 0u;
    __syncthreads();
    for (unsigned int i = crewid * 256 + tid; i < n; i += stride) {
        u64 key = cand[i];
        if ((unsigned int)(key >> 42) >= T) {
            unsigned int p = atomicAdd(&lc, 1u);
            if (p < BUFCAP) buf[p] = key;
        }
    }
    __syncthreads();
    unsigned int cc = lc < BUFCAP ? lc : BUFCAP;
    if (tid == 0) lb = atomicAdd(&cnt[1], cc);
    __syncthreads();
    unsigned int b2 = lb;
    for (unsigned int i = tid; i < cc; i += 256) {
        unsigned int p = b2 + i;
        if (p < (unsigned int)SG_CAP) SG[p] = buf[i];
    }
    gbar(barb + 2 * 576, crewid);                          // barrier 2
    unsigned int m2 = aload(&cnt[1]); if (m2 > (unsigned int)SG_CAP) m2 = SG_CAP;

    for (unsigned int i = tid; i < m2; i += 256) sgl[i] = SG[i];
    __syncthreads();
    for (unsigned int chunk = crewid * RB_ELEMS; chunk < m2;
         chunk += (unsigned int)CREW * RB_ELEMS) {
        u64 my[16];
        unsigned int r[16];
        #pragma unroll
        for (int i = 0; i < 16; ++i) {
            unsigned int e = chunk + wave * 16 + i;
            my[i] = (e < m2) ? sgl[e] : ~0ull;
            r[i] = 0u;
        }
        for (unsigned int j = ln; j < m2; j += 64) {
            u64 key = sgl[j];
            #pragma unroll
            for (int i = 0; i < 16; ++i) r[i] += (unsigned int)(key > my[i]);
        }
        #pragma unroll
        for (int i = 0; i < 16; ++i) {
            #pragma unroll
            for (int off = 32; off > 0; off >>= 1)
                r[i] += __shfl_down(r[i], off, 64);
            if (ln == 0) rnk[wave * 16 + i] = r[i];
        }
        __syncthreads();
        if (tid < RB_ELEMS) {
            unsigned int e = chunk + (unsigned int)tid;
            if (e < m2) {
                unsigned int rank = rnk[tid];
                if (rank < (unsigned int)K)
                    finalize_key(sgl[e], rank, low, cur, high, aff, out, K);
            }
        }
        __syncthreads();
    }
}

extern "C" void kernel_launch(void* const* d_in, const int* in_sizes, int n_in,
                              void* d_out, int out_size, void* d_ws, size_t ws_size,
                              hipStream_t stream) {
    const float* low  = (const float*)d_in[0];
    const float* cur  = (const float*)d_in[1];
    const float* high = (const float*)d_in[2];
    const float* aff  = (const float*)d_in[3];
    const float* oct  = (const float*)d_in[4];
    int K = (out_size - NPIX) / 7;   // 4096
    float* out = (float*)d_out;

    char* ws = (char*)d_ws;
    unsigned int* cnt   = (unsigned int*)ws;
    unsigned int* hist0 = (unsigned int*)(ws + 4096);
    unsigned int* hist1 = (unsigned int*)(ws + 12288);
    u64* SG             = (u64*)(ws + 20480);
    const size_t cand_off = 98304;
    u64* cand           = (u64*)(ws + cand_off);
    size_t cap_sz = ws_size > cand_off ? (ws_size - cand_off) / 8 : 0;
    if (cap_sz > (size_t)NPIX) cap_sz = (size_t)NPIX;
    unsigned int cap = (unsigned int)cap_sz;

    hipMemsetAsync(ws, 0, 20480, stream);   // cnt + barriers + hist0 + hist1

    dim3 gb(WW / 1024, HH / ROWS, 1);       // (2, 256) = 512 blocks
    nms_map_kernel<<<gb, 256, 0, stream>>>(low, cur, high, oct,
                                           out + (size_t)7 * K, out, 7 * K,
                                           cand, cnt, SG, cap);
    rank_kernel<<<RANK_BLOCKS, 256, 0, stream>>>(cand, SG, cnt, hist0, hist1,
                                                 cap, K, low, cur, high, aff, out);
}